// Round 1
// baseline (49.248 us; speedup 1.0000x reference)
//
#include <hip/hip_runtime.h>

namespace {
constexpr int D = 8;
constexpr int B = 2;
constexpr int N = 2048;
constexpr long long NN = (long long)N * N;
constexpr float ALPHA_P = 0.95f;   // pre-trace decay
constexpr float ALPHA_D = 0.90f;   // post-trace decay
constexpr float WMAX = 1.0f;
}

// One block per presynaptic row e. Threads stream over o with float4.
// Per-row scalars xbar_pre[d,b,e] / Xd[d,b,e] are block-uniform -> registers.
__global__ __launch_bounds__(256) void stdp_main(
    const float* __restrict__ Xd,
    const float* __restrict__ Xpost,
    const float* __restrict__ xbar_pre,
    const float* __restrict__ xbar_post,
    const float* __restrict__ W,
    const float* __restrict__ dmap,
    const float* __restrict__ A_p,
    const float* __restrict__ A_d,
    float* __restrict__ W_prev,
    float* __restrict__ W_new)
{
    const int e = blockIdx.x;

    // 32 block-uniform scalars for the d-contraction
    float xp[B][D];   // xbar_pre[d, b, e]
    float xs[B][D];   // Xd[d, b, e]
#pragma unroll
    for (int d = 0; d < D; ++d)
#pragma unroll
        for (int b = 0; b < B; ++b) {
            xp[b][d] = xbar_pre[(d * B + b) * N + e];
            xs[b][d] = Xd[(d * B + b) * N + e];
        }

    const long long row = (long long)e * N;

    for (int o = (int)threadIdx.x * 4; o < N; o += (int)blockDim.x * 4) {
        // 8 delay planes of dmap for this (e, o..o+3)
        float m[D][4];
#pragma unroll
        for (int d = 0; d < D; ++d) {
            const float4 v = *reinterpret_cast<const float4*>(dmap + d * NN + row + o);
            m[d][0] = v.x; m[d][1] = v.y; m[d][2] = v.z; m[d][3] = v.w;
        }
        const float4 apv = *reinterpret_cast<const float4*>(A_p + row + o);
        const float4 adv = *reinterpret_cast<const float4*>(A_d + row + o);
        const float ap[4] = {apv.x, apv.y, apv.z, apv.w};
        const float ad[4] = {adv.x, adv.y, adv.z, adv.w};

#pragma unroll
        for (int b = 0; b < B; ++b) {
            const float4 xpo4 = *reinterpret_cast<const float4*>(Xpost + b * N + o);
            const float4 xbp4 = *reinterpret_cast<const float4*>(xbar_post + b * N + o);
            const float xpo[4] = {xpo4.x, xpo4.y, xpo4.z, xpo4.w};
            const float xbp[4] = {xbp4.x, xbp4.y, xbp4.z, xbp4.w};

            const float4 wv = *reinterpret_cast<const float4*>(W + b * NN + row + o);
            const float w[4] = {wv.x, wv.y, wv.z, wv.w};

            float wn[4];
#pragma unroll
            for (int j = 0; j < 4; ++j) {
                float sp = 0.0f, sd = 0.0f;
#pragma unroll
                for (int d = 0; d < D; ++d) {
                    sp = fmaf(xp[b][d], m[d][j], sp);   // Σ_d xbar_pre * dmap
                    sd = fmaf(xs[b][d], m[d][j], sd);   // Σ_d Xd * dmap
                }
                const float dw = xpo[j] * sp * ap[j] - xbp[j] * sd * ad[j];
                wn[j] = fminf(fmaxf(w[j] + dw, 0.0f), WMAX);
            }

            *reinterpret_cast<float4*>(W_prev + b * NN + row + o) = wv;
            *reinterpret_cast<float4*>(W_new + b * NN + row + o) =
                make_float4(wn[0], wn[1], wn[2], wn[3]);
        }
    }
}

// Trace updates: xbar_pre_new = a_p*xbar_pre + (1-a_p)*Xd  (D*B*N elems)
//                xbar_post_new = a_d*xbar_post + (1-a_d)*Xpost (B*N elems)
__global__ __launch_bounds__(256) void stdp_traces(
    const float* __restrict__ Xd,
    const float* __restrict__ Xpost,
    const float* __restrict__ xbar_pre,
    const float* __restrict__ xbar_post,
    float* __restrict__ xbar_pre_new,
    float* __restrict__ xbar_post_new)
{
    const int i = blockIdx.x * blockDim.x + threadIdx.x;
    if (i < D * B * N)
        xbar_pre_new[i] = ALPHA_P * xbar_pre[i] + (1.0f - ALPHA_P) * Xd[i];
    if (i < B * N)
        xbar_post_new[i] = ALPHA_D * xbar_post[i] + (1.0f - ALPHA_D) * Xpost[i];
}

extern "C" void kernel_launch(void* const* d_in, const int* in_sizes, int n_in,
                              void* d_out, int out_size, void* d_ws, size_t ws_size,
                              hipStream_t stream) {
    const float* Xd        = (const float*)d_in[0];  // (D,B,N)
    const float* Xpost     = (const float*)d_in[1];  // (B,N)
    const float* xbar_pre  = (const float*)d_in[2];  // (D,B,N)
    const float* xbar_post = (const float*)d_in[3];  // (B,N)
    const float* W         = (const float*)d_in[4];  // (B,N,N)
    const float* dmap      = (const float*)d_in[5];  // (D,N,N)
    const float* A_p       = (const float*)d_in[6];  // (N,N)
    const float* A_d       = (const float*)d_in[7];  // (N,N)

    float* out = (float*)d_out;
    float* W_prev        = out;                          // B*N*N
    float* W_new         = W_prev + (size_t)B * NN;      // B*N*N
    float* xbar_pre_new  = W_new + (size_t)B * NN;       // D*B*N
    float* xbar_post_new = xbar_pre_new + (size_t)D * B * N; // B*N

    stdp_main<<<N, 256, 0, stream>>>(Xd, Xpost, xbar_pre, xbar_post, W, dmap,
                                     A_p, A_d, W_prev, W_new);

    const int trace_elems = D * B * N;
    stdp_traces<<<(trace_elems + 255) / 256, 256, 0, stream>>>(
        Xd, Xpost, xbar_pre, xbar_post, xbar_pre_new, xbar_post_new);
}

// Round 3
// 48.693 us; speedup vs baseline: 1.0114x; 1.0114x over previous
//
#include <hip/hip_runtime.h>

namespace {
constexpr int D = 8;
constexpr int B = 2;
constexpr int N = 2048;
constexpr long long NN = (long long)N * N;
constexpr float ALPHA_P = 0.95f;   // pre-trace decay
constexpr float ALPHA_D = 0.90f;   // post-trace decay
constexpr float WMAX = 1.0f;
}

// native clang vector (accepted by __builtin_nontemporal_*)
typedef float f32x4 __attribute__((ext_vector_type(4)));

// One block per presynaptic row e. Threads stream over o with 16B vectors.
// Per-row scalars xbar_pre[d,b,e] / Xd[d,b,e] are block-uniform.
// Cache policy: dmap/A_p/A_d are re-read every replay -> cached normally
// (L3-resident, 168 MB < 256 MB). W read + both output streams are
// touched once -> nontemporal, so they don't evict the resident set.
__global__ __launch_bounds__(256) void stdp_main(
    const float* __restrict__ Xd,
    const float* __restrict__ Xpost,
    const float* __restrict__ xbar_pre,
    const float* __restrict__ xbar_post,
    const float* __restrict__ W,
    const float* __restrict__ dmap,
    const float* __restrict__ A_p,
    const float* __restrict__ A_d,
    float* __restrict__ W_prev,
    float* __restrict__ W_new)
{
    const int e = blockIdx.x;

    // 32 block-uniform scalars for the d-contraction
    float xp[B][D];   // xbar_pre[d, b, e]
    float xs[B][D];   // Xd[d, b, e]
#pragma unroll
    for (int d = 0; d < D; ++d)
#pragma unroll
        for (int b = 0; b < B; ++b) {
            xp[b][d] = xbar_pre[(d * B + b) * N + e];
            xs[b][d] = Xd[(d * B + b) * N + e];
        }

    const long long row = (long long)e * N;

#pragma unroll
    for (int it = 0; it < N / (256 * 4); ++it) {
        const int o = (int)threadIdx.x * 4 + it * 256 * 4;

        // 8 delay planes of dmap for this (e, o..o+3) — keep cached
        f32x4 m[D];
#pragma unroll
        for (int d = 0; d < D; ++d)
            m[d] = *reinterpret_cast<const f32x4*>(dmap + d * NN + row + o);

        const f32x4 ap = *reinterpret_cast<const f32x4*>(A_p + row + o);
        const f32x4 ad = *reinterpret_cast<const f32x4*>(A_d + row + o);

#pragma unroll
        for (int b = 0; b < B; ++b) {
            const f32x4 xpo = *reinterpret_cast<const f32x4*>(Xpost + b * N + o);
            const f32x4 xbp = *reinterpret_cast<const f32x4*>(xbar_post + b * N + o);

            // W is consumed once per call -> nontemporal read
            const f32x4 wv = __builtin_nontemporal_load(
                reinterpret_cast<const f32x4*>(W + b * NN + row + o));

            f32x4 wn;
#pragma unroll
            for (int j = 0; j < 4; ++j) {
                float sp = 0.0f, sd = 0.0f;
#pragma unroll
                for (int d = 0; d < D; ++d) {
                    sp = fmaf(xp[b][d], m[d][j], sp);   // Σ_d xbar_pre * dmap
                    sd = fmaf(xs[b][d], m[d][j], sd);   // Σ_d Xd * dmap
                }
                const float dw = xpo[j] * sp * ap[j] - xbp[j] * sd * ad[j];
                wn[j] = fminf(fmaxf(wv[j] + dw, 0.0f), WMAX);
            }

            // outputs are never re-read -> nontemporal stores
            __builtin_nontemporal_store(
                wv, reinterpret_cast<f32x4*>(W_prev + b * NN + row + o));
            __builtin_nontemporal_store(
                wn, reinterpret_cast<f32x4*>(W_new + b * NN + row + o));
        }
    }
}

// Trace updates: xbar_pre_new = a_p*xbar_pre + (1-a_p)*Xd  (D*B*N elems)
//                xbar_post_new = a_d*xbar_post + (1-a_d)*Xpost (B*N elems)
__global__ __launch_bounds__(256) void stdp_traces(
    const float* __restrict__ Xd,
    const float* __restrict__ Xpost,
    const float* __restrict__ xbar_pre,
    const float* __restrict__ xbar_post,
    float* __restrict__ xbar_pre_new,
    float* __restrict__ xbar_post_new)
{
    const int i = blockIdx.x * blockDim.x + threadIdx.x;
    if (i < D * B * N)
        xbar_pre_new[i] = ALPHA_P * xbar_pre[i] + (1.0f - ALPHA_P) * Xd[i];
    if (i < B * N)
        xbar_post_new[i] = ALPHA_D * xbar_post[i] + (1.0f - ALPHA_D) * Xpost[i];
}

extern "C" void kernel_launch(void* const* d_in, const int* in_sizes, int n_in,
                              void* d_out, int out_size, void* d_ws, size_t ws_size,
                              hipStream_t stream) {
    const float* Xd        = (const float*)d_in[0];  // (D,B,N)
    const float* Xpost     = (const float*)d_in[1];  // (B,N)
    const float* xbar_pre  = (const float*)d_in[2];  // (D,B,N)
    const float* xbar_post = (const float*)d_in[3];  // (B,N)
    const float* W         = (const float*)d_in[4];  // (B,N,N)
    const float* dmap      = (const float*)d_in[5];  // (D,N,N)
    const float* A_p       = (const float*)d_in[6];  // (N,N)
    const float* A_d       = (const float*)d_in[7];  // (N,N)

    float* out = (float*)d_out;
    float* W_prev        = out;                          // B*N*N
    float* W_new         = W_prev + (size_t)B * NN;      // B*N*N
    float* xbar_pre_new  = W_new + (size_t)B * NN;       // D*B*N
    float* xbar_post_new = xbar_pre_new + (size_t)D * B * N; // B*N

    stdp_main<<<N, 256, 0, stream>>>(Xd, Xpost, xbar_pre, xbar_post, W, dmap,
                                     A_p, A_d, W_prev, W_new);

    const int trace_elems = D * B * N;
    stdp_traces<<<(trace_elems + 255) / 256, 256, 0, stream>>>(
        Xd, Xpost, xbar_pre, xbar_post, xbar_pre_new, xbar_post_new);
}